// Round 4
// baseline (112.439 us; speedup 1.0000x reference)
//
#include <hip/hip_runtime.h>

// RoI2Det, R15. Cost model (R11/R13/R14 fits): dur = ~58us fixed harness cost
// [~40us 256MiB ws poison fill @84% HBM peak (top-5 in R14's profile) + ~18us
// reset/gap machinery] + SUM(our kernel durations). Only lever: Sum(dur).
//
// Pipeline (4 dispatches):
//  0. hipMemsetAsync ghist (38KB, ~1.5us).
//  1. cand_kernel (500 blocks): softmax -> threshold -> per-block key segment
//     + count + global fine-histogram atomicAdd (~36/block, negligible).
//  2. nmsA_kernel (4 blocks): thresh FOLDED IN — waves 14/15 coarse-sum ghist
//     while waves 0..13 register-stage their key segments (no LDS keylist, all
//     loads in flight at once); wave 0 finishes T_A; filter+compact from regs
//     -> rank-sort -> decode -> IoU bit-matrix (4 words/row) -> DPP greedy
//     scan -> output. TARGET 192 / CAPA 256 (rank_100 ~110 on this input;
//     exactness preserved by the nkept<100 && K<Mtot guard -> nmsB).
//  3. nmsB_kernel (4 blocks): flag-gated exact fallback (unchanged).
//
// Exactness: greedy NMS output depends only on the sorted prefix down to the
// 100th survivor. Mode A sorts the exact top-S (S in [TARGET,CAPA]) selected
// by the monotone fine histogram. Guards (producer overflow, S_A>CAPA,
// nkept<100 with uncovered candidates) route to nmsB which redoes it exactly.
//
// ws: [0,2048) int gcnt[500]; [2048,514048) u64 keys[500][128];
//     [514048,514064) int gflag[4]; [514064,551952) u32 ghist[4][2368].
// key = (score_bits<<32) | (0xFFFFFFFF - flat_idx): desc order == lax.top_k.

typedef unsigned long long u64;
typedef unsigned int u32;

#define B_ 4
#define N_ 2000
#define C_ 80
#define NCLS 81
#define KPRE 2000
#define MAXDET 100
#define TARGET 192      // mode-A prefix floor (rank_100 ~ 110 observed)
#define NB 2312         // fine score buckets
#define NBPAD 2368      // 37*64
#define NG 37
#define HBASE 0xF500
#define KSHIFT 46       // key>>46 == score_bits>>14
#define CAPA 256
#define CAPB 2048
#define CAPBLK 128      // producer per-block key cap (expected ~36)
#define BPI 125         // producer blocks per image
#define SPW 9           // staged segments per wave (waves 0..13 cover 125)
#define BIGI 0x7fffffff

// ws offsets
#define WS_GCNT  0
#define WS_GKEYS 2048
#define WS_GFLAG 514048
#define WS_GHIST 514064   // 4*2368*4 = 37888 B

__device__ __forceinline__ u64 pack_key(float score, unsigned fi) {
  return ((u64)__float_as_uint(score) << 32) | (u64)(0xFFFFFFFFu - fi);
}
__device__ __forceinline__ int bucket_of_bits(u32 sb) {
  return min(max((int)(sb >> 14) - HBASE, 0), NB - 1);
}

// ---- wave64 reductions via DPP (VALU-only) ----
__device__ __forceinline__ float wred_max(float v) {
  int t;
#define STEPM(ctrl)                                                          \
  t = __builtin_amdgcn_update_dpp(__float_as_int(v), __float_as_int(v),      \
                                  (ctrl), 0xF, 0xF, false);                  \
  v = fmaxf(v, __int_as_float(t));
  STEPM(0x111) STEPM(0x112) STEPM(0x114) STEPM(0x118) STEPM(0x142) STEPM(0x143)
#undef STEPM
  return __int_as_float(__builtin_amdgcn_readlane(__float_as_int(v), 63));
}
__device__ __forceinline__ float wred_sum(float v) {
  int t;
#define STEPS(ctrl)                                                          \
  t = __builtin_amdgcn_update_dpp(0, __float_as_int(v), (ctrl), 0xF, 0xF,    \
                                  false);                                    \
  v = v + __int_as_float(t);
  STEPS(0x111) STEPS(0x112) STEPS(0x114) STEPS(0x118) STEPS(0x142) STEPS(0x143)
#undef STEPS
  return __int_as_float(__builtin_amdgcn_readlane(__float_as_int(v), 63));
}

// min over lanes 0..7 (others hold BIGI); result valid in lane 0 (row_shl).
__device__ __forceinline__ int dpp_min8(int v) {
  int t;
  t = __builtin_amdgcn_update_dpp(BIGI, v, 0x104, 0xF, 0xF, false);
  v = min(v, t);
  t = __builtin_amdgcn_update_dpp(BIGI, v, 0x102, 0xF, 0xF, false);
  v = min(v, t);
  t = __builtin_amdgcn_update_dpp(BIGI, v, 0x101, 0xF, 0xF, false);
  v = min(v, t);
  return v;
}

__device__ __forceinline__ float4 decode_one(
    u64 kk, const float* __restrict__ reg, const float* __restrict__ props,
    int b, float h, float w, float offscale) {
  const float MAXR = 4.135166556742356f;  // |log(16/1000)|
  unsigned fi = 0xFFFFFFFFu - (u32)kk;
  int n = (int)(fi / (unsigned)C_);
  int c = (int)(fi - (unsigned)n * (unsigned)C_);
  float4 p = ((const float4*)props)[b * N_ + n];
  const float* dl = reg + ((size_t)(b * N_ + n)) * (C_ * 4) + c * 4;
  float dx = dl[0] * 0.1f;
  float dy = dl[1] * 0.1f;
  float dw = fminf(fmaxf(dl[2] * 0.2f, -MAXR), MAXR);
  float dh = fminf(fmaxf(dl[3] * 0.2f, -MAXR), MAXR);
  float px = (p.x + p.z) * 0.5f, py = (p.y + p.w) * 0.5f;
  float pw = p.z - p.x, ph = p.w - p.y;
  float gx = px + pw * dx, gy = py + ph * dy;
  float gw = pw * expf(dw), gh = ph * expf(dh);
  float off = (float)c * offscale;  // cross-class IoU exactly 0 after offset
  return make_float4(fminf(fmaxf(gx - gw * 0.5f, 0.0f), w) + off,
                     fminf(fmaxf(gy - gh * 0.5f, 0.0f), h) + off,
                     fminf(fmaxf(gx + gw * 0.5f, 0.0f), w) + off,
                     fminf(fmaxf(gy + gh * 0.5f, 0.0f), h) + off);
}

// ---------------- producer: softmax -> keys + global histogram ----------------
__global__ __launch_bounds__(1024) void cand_kernel(
    const float* __restrict__ cls, u64* __restrict__ gkeys,
    int* __restrict__ gcnt, u32* __restrict__ ghist) {
  __shared__ int s_wc[16], s_woff[16];
  const int tid = threadIdx.x;
  const int w = tid >> 6, lane = tid & 63;
  const int blk = blockIdx.x;
  const int b = blk / BPI;
  const int n = (blk % BPI) * 16 + w;
  const float* lg = cls + (size_t)(b * N_ + n) * NCLS;
  float x0 = lg[lane];
  float x1 = (lane < 17) ? lg[64 + lane] : -3.0e38f;
  float mx = wred_max(fmaxf(x0, x1));
  float e0 = expf(x0 - mx);
  float e1 = (lane < 17) ? expf(x1 - mx) : 0.0f;
  float sum = wred_sum(e0 + e1);
  float sc0 = e0 / sum, sc1 = e1 / sum;
  bool p0 = sc0 > 0.05f;
  bool p1 = (lane < 16) && (sc1 > 0.05f);  // class 80 = background
  u64 m0 = __ballot(p0), m1 = __ballot(p1);
  int c0 = __popcll(m0);
  if (lane == 0) s_wc[w] = c0 + __popcll(m1);
  __syncthreads();
  if (tid == 0) {
    int acc = 0;
#pragma unroll
    for (int i = 0; i < 16; ++i) { s_woff[i] = acc; acc += s_wc[i]; }
    gcnt[blk] = acc;  // unconditional: stale/poisoned ws never observed
  }
  __syncthreads();
  const int base = s_woff[w];
  const u64 lt = (1ull << lane) - 1;
  u64* gk = gkeys + (size_t)blk * CAPBLK;
  u32* gh = ghist + (size_t)b * NBPAD;
  if (p0) {
    int slot = base + __popcll(m0 & lt);
    if (slot < CAPBLK) gk[slot] = pack_key(sc0, (unsigned)(n * C_ + lane));
    atomicAdd(&gh[bucket_of_bits(__float_as_uint(sc0))], 1u);
  }
  if (p1) {
    int slot = base + c0 + __popcll(m1 & lt);
    if (slot < CAPBLK) gk[slot] = pack_key(sc1, (unsigned)(n * C_ + 64 + lane));
    atomicAdd(&gh[bucket_of_bits(__float_as_uint(sc1))], 1u);
  }
}

// ---------------- nmsA: hot path, thresh folded in ----------------
// LDS map (17248 B): SS u64[256]@0; U u64[260]@2048; rb u64[256*4]@4128;
// bxA float4[256]@12320; outl int[128]@16416; misc int[16]@16928;
// s_coarse int[64]@16992.  misc: 0=T_A 2=S_A 3=Mtot 4=cnt 6=nkept 7=ovf
__global__ __launch_bounds__(1024) void nmsA_kernel(
    const float* __restrict__ reg, const float* __restrict__ props,
    const int* __restrict__ hw, const u64* __restrict__ gkeys,
    const int* __restrict__ gcnt, const u32* __restrict__ ghist,
    int* __restrict__ gflag, float* __restrict__ out) {
  __shared__ u64 lds8[2156];  // 17248 B
  char* bp = (char*)lds8;
  u64* SS = (u64*)bp;
  u64* U = (u64*)(bp + 2048);
  u64* rb = (u64*)(bp + 4128);
  float4* bxA = (float4*)(bp + 12320);
  int* outl = (int*)(bp + 16416);
  int* misc = (int*)(bp + 16928);
  int* s_coarse = (int*)(bp + 16992);

  const int b = blockIdx.x, tid = threadIdx.x;
  const int wv = tid >> 6, lane = tid & 63;

  float h = (float)hw[b * 2 + 0];
  float w = (float)hw[b * 2 + 1];
  float offscale = fmaxf(h, w) + 1.0f;

  if (tid < 16) misc[tid] = 0;
  if (tid >= NG && tid < 64) s_coarse[tid] = 0;  // waves 14/15 fill [0,NG)

  // ---- Phase A (parallel): waves 0..13 stage keys into registers;
  //      waves 14/15 coarse-sum the global fine histogram. ----
  int cnts[SPW];
  u64 ka[SPW], kb[SPW];
  if (wv < 14) {
#pragma unroll
    for (int k = 0; k < SPW; k++) {
      int p = wv * SPW + k;
      cnts[k] = (p < BPI) ? gcnt[b * BPI + p] : 0;
    }
#pragma unroll
    for (int k = 0; k < SPW; k++) {
      int p = wv * SPW + k;
      int cnt = min(cnts[k], CAPBLK);
      const u64* seg = gkeys + (size_t)(b * BPI + p) * CAPBLK;
      ka[k] = (lane < cnt) ? seg[lane] : 0ULL;
      kb[k] = (64 + lane < cnt) ? seg[64 + lane] : 0ULL;
    }
  } else {
    // wave 14: groups 0..18; wave 15: groups 19..36
    int g0 = (wv == 14) ? 0 : 19;
    int g1 = (wv == 14) ? 19 : NG;
    for (int g2 = g0; g2 < g1; g2++) {
      int v = (int)ghist[b * NBPAD + ((g2 << 6) | lane)];
#pragma unroll
      for (int o = 32; o; o >>= 1) v += __shfl_xor(v, o);
      if (lane == 0) s_coarse[g2] = v;
    }
  }
  __syncthreads();

  // ---- Phase B: wave 0 computes T_A (cum>=TARGET), S_A, Mtot. ----
  if (tid < 64) {
    int v = s_coarse[lane];
#pragma unroll
    for (int off = 1; off < 64; off <<= 1) {
      int src = lane + off;
      int o = __shfl(v, src < 64 ? src : 63);
      if (src < 64) v += o;
    }
    int Mtot = __shfl(v, 0);
    u64 pm = __ballot(v >= TARGET);
    int T_A = 0, S_A;
    if (pm) {
      int gs = 63 - __builtin_clzll(pm);
      int beyond = __shfl(v, gs + 1);
      int fv = (int)ghist[b * NBPAD + ((gs << 6) | lane)];
#pragma unroll
      for (int off = 1; off < 64; off <<= 1) {
        int src = lane + off;
        int o = __shfl(fv, src < 64 ? src : 63);
        if (src < 64) fv += o;
      }
      int cum = beyond + fv;
      u64 pm2 = __ballot(cum >= TARGET);
      int tr = 63 - __builtin_clzll(pm2);
      T_A = (gs << 6) + tr;
      S_A = __shfl(cum, tr);
    } else {
      S_A = Mtot;
    }
    if (lane == 0) { misc[0] = T_A; misc[2] = S_A; misc[3] = Mtot; }
  }
  __syncthreads();

  const int T_A = misc[0], S_A = misc[2], Mtot = misc[3];
  bool modeB = (S_A > CAPA);
  int K = 0, nkept = 0;

  if (!modeB) {
    // ---- Phase C: filter staged keys by T_A, ballot-compact into U. ----
    if (wv < 14) {
      bool ovf = false;
      const u64 lt = (1ull << lane) - 1;
#pragma unroll
      for (int k = 0; k < SPW; k++) {
        int cnt = cnts[k];
        if (cnt > CAPBLK) { ovf = true; cnt = CAPBLK; }
        bool pr = (lane < cnt) &&
                  (bucket_of_bits((u32)(ka[k] >> 32)) >= T_A);
        u64 mk = __ballot(pr);
        if (mk) {
          int wbase = 0;
          if (lane == 0) wbase = atomicAdd(&misc[4], __popcll(mk));
          wbase = __shfl(wbase, 0);
          if (pr) {
            int pos = wbase + __popcll(mk & lt);
            if (pos < CAPA) U[pos] = ka[k];
          }
        }
        pr = (64 + lane < cnt) &&
             (bucket_of_bits((u32)(kb[k] >> 32)) >= T_A);
        mk = __ballot(pr);
        if (mk) {
          int wbase = 0;
          if (lane == 0) wbase = atomicAdd(&misc[4], __popcll(mk));
          wbase = __shfl(wbase, 0);
          if (pr) {
            int pos = wbase + __popcll(mk & lt);
            if (pos < CAPA) U[pos] = kb[k];
          }
        }
      }
      if (lane == 0 && ovf) misc[7] = 1;
    }
    __syncthreads();
    if (misc[7]) modeB = true;
    int S = misc[4];
    if (S > CAPA) S = CAPA;

    if (!modeB) {
      // ---- Phase D: rank-scatter sort U -> SS. ----
      if (tid == 0 && (S & 1)) U[S] = 0ULL;
      __syncthreads();
      if (tid < S) {
        u64 k1 = U[tid];
        int r1 = 0;
        const ulonglong2* Uu2 = (const ulonglong2*)U;
        int half = (S + 1) >> 1;
        for (int k = 0; k < half; k++) {
          ulonglong2 kk = Uu2[k];
          r1 += (kk.x > k1) + (kk.y > k1);
        }
        SS[r1] = k1;
      }
      __syncthreads();
      K = S;
      for (int j = tid; j < K; j += 1024)
        bxA[j] = decode_one(SS[j], reg, props, b, h, w, offscale);
      __syncthreads();

      // ---- Phase E: suppression bit-matrix (4 words/row). ----
      int nwords = (S + 63) >> 6;
      int ntiles = nwords * (nwords + 1) / 2;
      for (int t = wv; t < ntiles; t += 16) {
        int ti = 0, rem = t;
        while (rem >= nwords - ti) { rem -= nwords - ti; ti++; }
        int tj = ti + rem;
        int i = (ti << 6) + lane;
        float4 bi4 = bxA[i];
        float ai = (bi4.z - bi4.x) * (bi4.w - bi4.y);
        u64 bits = 0;
        int jbase = tj << 6;
        int jcount = min(64, S - jbase);
        for (int jj = 0; jj < jcount; jj++) {
          int j = jbase + jj;
          float4 bj = bxA[j];
          float aj = (bj.z - bj.x) * (bj.w - bj.y);
          float iw = fmaxf(fminf(bi4.z, bj.z) - fmaxf(bi4.x, bj.x), 0.0f);
          float ih = fmaxf(fminf(bi4.w, bj.w) - fmaxf(bi4.y, bj.y), 0.0f);
          float inter = iw * ih;
          float iou = inter / (ai + aj - inter + 1e-6f);
          if (j > i && iou > 0.5f) bits |= (1ull << jj);
        }
        if (i < S) rb[i * 4 + tj] = bits;
      }
      __syncthreads();

      // ---- Phase F: greedy bit-scan (wave 0), speculative i+1 prefetch. ----
      if (tid < 64) {
        int nw7 = (S + 63) >> 6;
        u64 alive = 0;
        if (lane < nw7) {
          alive = ~0ull;
          int remb = S & 63;
          if (lane == nw7 - 1 && remb) alive = (1ull << remb) - 1;
        }
        int nk = 0;
        if (S > 0) {
          int i = 0;
          u64 row = (lane < nw7) ? rb[0 * 4 + lane] : 0ull;
          for (;;) {
            if (lane == 0) outl[nk] = i;
            nk++;
            if (nk >= MAXDET) break;
            if (lane == (i >> 6)) alive &= ~(1ull << (i & 63));
            u64 rowSpec = (i + 1 < S && lane < nw7) ? rb[(i + 1) * 4 + lane] : 0ull;
            u64 a2 = alive & ~row;
            alive = a2;
            int cnd = a2 ? ((lane << 6) + (int)__builtin_ctzll(a2)) : BIGI;
            int m8 = dpp_min8(cnd);
            int ni = __builtin_amdgcn_readfirstlane(m8);
            if (ni >= BIGI) break;
            row = (ni == i + 1) ? rowSpec
                                : ((lane < nw7) ? rb[ni * 4 + lane] : 0ull);
            i = ni;
          }
        }
        if (lane == 0) misc[6] = nk;
      }
      __syncthreads();
      nkept = misc[6];
      if (nkept < MAXDET && K < Mtot && K < KPRE) modeB = true;
    }
  }

  if (tid == 0) gflag[b] = modeB ? 1 : 0;  // unconditional each launch
  if (modeB) return;  // nmsB writes this image's output

  // Output: boxes [B,100,4] | scores [B,100] | labels [B,100].
  float* oBox = out;
  float* oSc = out + B_ * MAXDET * 4;
  float* oLb = out + B_ * MAXDET * 5;
  for (int k2 = tid; k2 < MAXDET; k2 += 1024) {
    float4 bb = make_float4(0.0f, 0.0f, 0.0f, 0.0f);
    float sv = 0.0f, lv = -1.0f;
    if (k2 < nkept) {
      int idx = outl[k2];
      u64 kk = SS[idx];
      sv = __uint_as_float((u32)(kk >> 32));
      unsigned fi = 0xFFFFFFFFu - (u32)kk;
      int c = (int)(fi % (unsigned)C_);
      float off = (float)c * offscale;
      float4 ob = bxA[idx];
      bb = make_float4(ob.x - off, ob.y - off, ob.z - off, ob.w - off);
      lv = (float)c;
    }
    oBox[(b * MAXDET + k2) * 4 + 0] = bb.x;
    oBox[(b * MAXDET + k2) * 4 + 1] = bb.y;
    oBox[(b * MAXDET + k2) * 4 + 2] = bb.z;
    oBox[(b * MAXDET + k2) * 4 + 3] = bb.w;
    oSc[b * MAXDET + k2] = sv;
    oLb[b * MAXDET + k2] = lv;
  }
}

// ---------------- nmsB: exact fallback (flag-gated) ----------------
__global__ __launch_bounds__(1024) void nmsB_kernel(
    const float* __restrict__ reg, const float* __restrict__ props,
    const int* __restrict__ hw, const u64* __restrict__ gkeys,
    const int* __restrict__ gcnt, const int* __restrict__ gflag,
    float* __restrict__ out) {
  const int b = blockIdx.x, tid = threadIdx.x;
  if (gflag[b] == 0) return;  // block-uniform fast exit (the normal case)

  __shared__ u64 lds8[7952];
  char* bp = (char*)lds8;
  u32* hist = (u32*)(bp + 0);          // [0,9472)
  u64* U2 = (u64*)(bp + 9472);         // 2048 keys
  u64* SSB = (u64*)(bp + 25856);       // 2048 sorted
  int* outl = (int*)(bp + 42240);      // 128
  int* misc = (int*)(bp + 42752);      // 16
  const int wv = tid >> 6, lane = tid & 63;

  float h = (float)hw[b * 2 + 0];
  float w = (float)hw[b * 2 + 1];
  float offscale = fmaxf(h, w) + 1.0f;

  for (int i = tid; i < NBPAD; i += 1024) hist[i] = 0;
  if (tid < 16) misc[tid] = 0;
  __syncthreads();

  // Histogram from stored global keys.
  for (int k = 0; k < 8; k++) {
    int p = wv + 16 * k;
    if (p >= BPI) break;
    int cnt = min(gcnt[b * BPI + p], CAPBLK);
    const u64* seg = gkeys + (size_t)(b * BPI + p) * CAPBLK;
#pragma unroll
    for (int r = 0; r < 2; r++) {
      int idx = lane + 64 * r;
      if (idx < cnt) {
        u64 key = seg[idx];
        int bi = min(max((int)(key >> KSHIFT) - HBASE, 0), NB - 1);
        atomicAdd(&hist[bi], 1u);
      }
    }
  }
  __syncthreads();

  // T_B: serial suffix walk (cold path).
  if (tid == 0) {
    int acc = 0, tb = 0;
    for (int bi = NB - 1; bi >= 0; bi--) {
      acc += (int)hist[bi];
      if (acc >= KPRE) { tb = bi; break; }
    }
    if (acc > CAPB) tb = min(tb + 1, NB - 1);  // fat-bucket guard
    misc[1] = tb;
    misc[4] = 0;
  }
  __syncthreads();
  int T_B = misc[1];

  // Compact bucket >= T_B into U2 (ballot-aggregated).
  for (int k = 0; k < 8; k++) {
    int p = wv + 16 * k;
    if (p >= BPI) break;
    int cnt = min(gcnt[b * BPI + p], CAPBLK);
    const u64* seg = gkeys + (size_t)(b * BPI + p) * CAPBLK;
#pragma unroll
    for (int r = 0; r < 2; r++) {
      int idx = lane + 64 * r;
      bool pred = false;
      u64 key = 0;
      if (idx < cnt) {
        key = seg[idx];
        int bi = min(max((int)(key >> KSHIFT) - HBASE, 0), NB - 1);
        pred = (bi >= T_B);
      }
      u64 mk = __ballot(pred);
      if (mk) {
        int wbase = 0;
        if (lane == 0) wbase = atomicAdd(&misc[4], __popcll(mk));
        wbase = __shfl(wbase, 0);
        if (pred) {
          int pos = wbase + __popcll(mk & ((1ull << lane) - 1));
          if (pos < CAPB) U2[pos] = key;
        }
      }
    }
  }
  __syncthreads();
  int S = misc[4];
  if (S > CAPB) S = CAPB;
  {  // rank-scatter sort, 2 keys/thread
    int j1 = tid, j2 = tid + 1024;
    u64 k1 = (j1 < S) ? U2[j1] : 0ULL;
    u64 k2 = (j2 < S) ? U2[j2] : 0ULL;
    int r1 = 0, r2 = 0;
    for (int k = 0; k < S; k++) {
      u64 kk = U2[k];
      r1 += (kk > k1);
      r2 += (kk > k2);
    }
    __syncthreads();
    if (j1 < S) SSB[r1] = k1;
    if (j2 < S) SSB[r2] = k2;
  }
  __syncthreads();
  int K = (S < KPRE) ? S : KPRE;  // exact top-2000 (or all if fewer)
  // NMS with per-thread register boxes.
  int j1 = tid, j2 = tid + 1024;
  bool kp1 = (j1 < K), kp2 = (j2 < K);
  float4 bb1 = kp1 ? decode_one(SSB[j1], reg, props, b, h, w, offscale)
                   : make_float4(0, 0, 0, 0);
  float4 bb2 = kp2 ? decode_one(SSB[j2], reg, props, b, h, w, offscale)
                   : make_float4(0, 0, 0, 0);
  int nk = 0;
  if (K > 0) {
    int i = 0;
    for (;;) {
      if (tid == 0) { outl[nk] = i; misc[5] = K; }
      nk++;
      if (nk >= MAXDET) break;
      __syncthreads();
      float4 tb = decode_one(SSB[i], reg, props, b, h, w, offscale);
      float ai = (tb.z - tb.x) * (tb.w - tb.y);
      int ln = K;
      if (kp1 && j1 > i) {
        float aj = (bb1.z - bb1.x) * (bb1.w - bb1.y);
        float iw = fmaxf(fminf(tb.z, bb1.z) - fmaxf(tb.x, bb1.x), 0.0f);
        float ih = fmaxf(fminf(tb.w, bb1.w) - fmaxf(tb.y, bb1.y), 0.0f);
        float inter = iw * ih;
        float iou = inter / (ai + aj - inter + 1e-6f);
        if (iou > 0.5f) kp1 = false;
        else ln = min(ln, j1);
      }
      if (kp2 && j2 > i) {
        float aj = (bb2.z - bb2.x) * (bb2.w - bb2.y);
        float iw = fmaxf(fminf(tb.z, bb2.z) - fmaxf(tb.x, bb2.x), 0.0f);
        float ih = fmaxf(fminf(tb.w, bb2.w) - fmaxf(tb.y, bb2.y), 0.0f);
        float inter = iw * ih;
        float iou = inter / (ai + aj - inter + 1e-6f);
        if (iou > 0.5f) kp2 = false;
        else ln = min(ln, j2);
      }
#pragma unroll
      for (int off = 32; off; off >>= 1) ln = min(ln, __shfl_xor(ln, off));
      if ((tid & 63) == 0 && ln < K) atomicMin(&misc[5], ln);
      __syncthreads();
      int ni = misc[5];
      __syncthreads();
      if (ni >= K) break;
      i = ni;
    }
  }
  if (tid == 0) misc[6] = nk;
  __syncthreads();
  int nkept = misc[6];

  float* oBox = out;
  float* oSc = out + B_ * MAXDET * 4;
  float* oLb = out + B_ * MAXDET * 5;
  for (int k2 = tid; k2 < MAXDET; k2 += 1024) {
    float4 bb = make_float4(0.0f, 0.0f, 0.0f, 0.0f);
    float sv = 0.0f, lv = -1.0f;
    if (k2 < nkept) {
      int idx = outl[k2];
      u64 kk = SSB[idx];
      sv = __uint_as_float((u32)(kk >> 32));
      unsigned fi = 0xFFFFFFFFu - (u32)kk;
      int c = (int)(fi % (unsigned)C_);
      float off = (float)c * offscale;
      float4 ob = decode_one(kk, reg, props, b, h, w, offscale);
      bb = make_float4(ob.x - off, ob.y - off, ob.z - off, ob.w - off);
      lv = (float)c;
    }
    oBox[(b * MAXDET + k2) * 4 + 0] = bb.x;
    oBox[(b * MAXDET + k2) * 4 + 1] = bb.y;
    oBox[(b * MAXDET + k2) * 4 + 2] = bb.z;
    oBox[(b * MAXDET + k2) * 4 + 3] = bb.w;
    oSc[b * MAXDET + k2] = sv;
    oLb[b * MAXDET + k2] = lv;
  }
}

extern "C" void kernel_launch(void* const* d_in, const int* in_sizes, int n_in,
                              void* d_out, int out_size, void* d_ws, size_t ws_size,
                              hipStream_t stream) {
  const float* cls = (const float*)d_in[0];    // [B,N,81] f32
  const float* reg = (const float*)d_in[1];    // [B,N,320] f32
  const float* props = (const float*)d_in[2];  // [B,N,4] f32
  const int* hw = (const int*)d_in[3];         // [B,2] i32
  float* out = (float*)d_out;                  // 2400 f32

  int* gcnt = (int*)((char*)d_ws + WS_GCNT);
  u64* gkeys = (u64*)((char*)d_ws + WS_GKEYS);
  int* gflag = (int*)((char*)d_ws + WS_GFLAG);
  u32* ghist = (u32*)((char*)d_ws + WS_GHIST);

  hipMemsetAsync(ghist, 0, (size_t)B_ * NBPAD * 4, stream);
  cand_kernel<<<B_ * BPI, 1024, 0, stream>>>(cls, gkeys, gcnt, ghist);
  nmsA_kernel<<<B_, 1024, 0, stream>>>(reg, props, hw, gkeys, gcnt, ghist,
                                       gflag, out);
  nmsB_kernel<<<B_, 1024, 0, stream>>>(reg, props, hw, gkeys, gcnt, gflag, out);
}

// Round 5
// 109.511 us; speedup vs baseline: 1.0267x; 1.0267x over previous
//
#include <hip/hip_runtime.h>

// RoI2Det, R16. Cost model (R11..R15 fits): wall = ~58us fixed harness cost
// (256MiB ws poison fill ~40us @84% HBM + reset machinery) + SUM(kernel durs),
// launch-count-independent. nmsA is pinned at ~40-43us across FOUR interior
// rebuilds => latency-bound, not throughput. Prime suspect: scattered ingest
// (125 segments/image, stride 1KB, cross-XCD producers => ~18 serialized HBM
// latency rounds). Fix: CONTIGUOUS per-image key buffer.
//
//  0. hipMemsetAsync ws[0,37952) — gcur[4] + ghist[4][2368].
//  1. cand_kernel (500 blocks): softmax -> threshold -> per-image atomic
//     cursor -> CONTIGUOUS key writes + fine-histogram atomicAdd.
//     No per-block cap: mode A is exact whenever M <= CAPIMG (8192).
//  2. nmsA_kernel (4 blocks): all waves register-stage 8 contiguous key
//     rounds (one latency round) while waves 12..15 coarse-sum ghist; wave 0
//     finishes T_A; filter+compact from regs -> rank-sort -> decode -> IoU
//     bit-matrix -> DPP greedy scan -> output. TARGET 192 / CAPA 256.
//  3. nmsB_kernel (4 blocks): flag-gated exact fallback from the contiguous
//     buffer (top-<=2048 covers reference top-2000 prefix need).
//
// Exactness: greedy NMS output depends only on the sorted prefix down to the
// 100th survivor. Mode A sorts the exact top-S (S in [TARGET,CAPA]) selected
// by the monotone fine histogram. Guards (M>CAPIMG, S_A>CAPA, nkept<100 with
// uncovered candidates) route to nmsB. Key set is cursor-order-
// nondeterministic but keys are unique => sort output deterministic.
//
// ws: [0,16) u32 gcur[4] (memset); [64,37952) u32 ghist[4][2368] (memset);
//     [37952,37968) int gflag[4]; [38016,300160) u64 gkeys[4][8192].
// key = (score_bits<<32) | (0xFFFFFFFF - flat_idx): desc order == lax.top_k.

typedef unsigned long long u64;
typedef unsigned int u32;

#define B_ 4
#define N_ 2000
#define C_ 80
#define NCLS 81
#define KPRE 2000
#define MAXDET 100
#define TARGET 192      // mode-A prefix floor (rank_100 ~ 110 observed)
#define NB 2312         // fine score buckets
#define NBPAD 2368      // 37*64
#define NG 37
#define HBASE 0xF500
#define KSHIFT 46       // key>>46 == score_bits>>14
#define CAPA 256
#define CAPB 2048
#define CAPIMG 8192     // per-image contiguous key cap (expected M ~ 4500)
#define KPT 8           // staged key rounds per thread (8*1024 = CAPIMG)
#define BPI 125         // producer blocks per image
#define BIGI 0x7fffffff

// ws offsets
#define WS_GCUR  0       // 4*u32, memset
#define WS_GHIST 64      // 4*2368*4 = 37888, memset ends 37952
#define WS_GFLAG 37952   // 4*int
#define WS_GKEYS 38016   // 4*8192*8 = 262144, ends 300160
#define WS_ZEND  37952   // memset [0, WS_ZEND)

__device__ __forceinline__ u64 pack_key(float score, unsigned fi) {
  return ((u64)__float_as_uint(score) << 32) | (u64)(0xFFFFFFFFu - fi);
}
__device__ __forceinline__ int bucket_of_bits(u32 sb) {
  return min(max((int)(sb >> 14) - HBASE, 0), NB - 1);
}

// ---- wave64 reductions via DPP (VALU-only) ----
__device__ __forceinline__ float wred_max(float v) {
  int t;
#define STEPM(ctrl)                                                          \
  t = __builtin_amdgcn_update_dpp(__float_as_int(v), __float_as_int(v),      \
                                  (ctrl), 0xF, 0xF, false);                  \
  v = fmaxf(v, __int_as_float(t));
  STEPM(0x111) STEPM(0x112) STEPM(0x114) STEPM(0x118) STEPM(0x142) STEPM(0x143)
#undef STEPM
  return __int_as_float(__builtin_amdgcn_readlane(__float_as_int(v), 63));
}
__device__ __forceinline__ float wred_sum(float v) {
  int t;
#define STEPS(ctrl)                                                          \
  t = __builtin_amdgcn_update_dpp(0, __float_as_int(v), (ctrl), 0xF, 0xF,    \
                                  false);                                    \
  v = v + __int_as_float(t);
  STEPS(0x111) STEPS(0x112) STEPS(0x114) STEPS(0x118) STEPS(0x142) STEPS(0x143)
#undef STEPS
  return __int_as_float(__builtin_amdgcn_readlane(__float_as_int(v), 63));
}

// min over lanes 0..7 (others hold BIGI); result valid in lane 0 (row_shl).
__device__ __forceinline__ int dpp_min8(int v) {
  int t;
  t = __builtin_amdgcn_update_dpp(BIGI, v, 0x104, 0xF, 0xF, false);
  v = min(v, t);
  t = __builtin_amdgcn_update_dpp(BIGI, v, 0x102, 0xF, 0xF, false);
  v = min(v, t);
  t = __builtin_amdgcn_update_dpp(BIGI, v, 0x101, 0xF, 0xF, false);
  v = min(v, t);
  return v;
}

__device__ __forceinline__ float4 decode_one(
    u64 kk, const float* __restrict__ reg, const float* __restrict__ props,
    int b, float h, float w, float offscale) {
  const float MAXR = 4.135166556742356f;  // |log(16/1000)|
  unsigned fi = 0xFFFFFFFFu - (u32)kk;
  int n = (int)(fi / (unsigned)C_);
  int c = (int)(fi - (unsigned)n * (unsigned)C_);
  float4 p = ((const float4*)props)[b * N_ + n];
  const float* dl = reg + ((size_t)(b * N_ + n)) * (C_ * 4) + c * 4;
  float dx = dl[0] * 0.1f;
  float dy = dl[1] * 0.1f;
  float dw = fminf(fmaxf(dl[2] * 0.2f, -MAXR), MAXR);
  float dh = fminf(fmaxf(dl[3] * 0.2f, -MAXR), MAXR);
  float px = (p.x + p.z) * 0.5f, py = (p.y + p.w) * 0.5f;
  float pw = p.z - p.x, ph = p.w - p.y;
  float gx = px + pw * dx, gy = py + ph * dy;
  float gw = pw * expf(dw), gh = ph * expf(dh);
  float off = (float)c * offscale;  // cross-class IoU exactly 0 after offset
  return make_float4(fminf(fmaxf(gx - gw * 0.5f, 0.0f), w) + off,
                     fminf(fmaxf(gy - gh * 0.5f, 0.0f), h) + off,
                     fminf(fmaxf(gx + gw * 0.5f, 0.0f), w) + off,
                     fminf(fmaxf(gy + gh * 0.5f, 0.0f), h) + off);
}

// ------- producer: softmax -> contiguous keys (atomic cursor) + ghist -------
__global__ __launch_bounds__(1024) void cand_kernel(
    const float* __restrict__ cls, u64* __restrict__ gkeys,
    u32* __restrict__ gcur, u32* __restrict__ ghist) {
  __shared__ int s_wc[16], s_woff[16];
  __shared__ int s_base;
  const int tid = threadIdx.x;
  const int w = tid >> 6, lane = tid & 63;
  const int blk = blockIdx.x;
  const int b = blk / BPI;
  const int n = (blk % BPI) * 16 + w;
  const float* lg = cls + (size_t)(b * N_ + n) * NCLS;
  float x0 = lg[lane];
  float x1 = (lane < 17) ? lg[64 + lane] : -3.0e38f;
  float mx = wred_max(fmaxf(x0, x1));
  float e0 = expf(x0 - mx);
  float e1 = (lane < 17) ? expf(x1 - mx) : 0.0f;
  float sum = wred_sum(e0 + e1);
  float sc0 = e0 / sum, sc1 = e1 / sum;
  bool p0 = sc0 > 0.05f;
  bool p1 = (lane < 16) && (sc1 > 0.05f);  // class 80 = background
  u64 m0 = __ballot(p0), m1 = __ballot(p1);
  int c0 = __popcll(m0);
  if (lane == 0) s_wc[w] = c0 + __popcll(m1);
  __syncthreads();
  if (tid == 0) {
    int acc = 0;
#pragma unroll
    for (int i = 0; i < 16; ++i) { s_woff[i] = acc; acc += s_wc[i]; }
    s_base = (acc > 0) ? (int)atomicAdd(&gcur[b], (u32)acc) : 0;
  }
  __syncthreads();
  const int base = s_base + s_woff[w];
  const u64 lt = (1ull << lane) - 1;
  u64* gk = gkeys + (size_t)b * CAPIMG;
  u32* gh = ghist + (size_t)b * NBPAD;
  if (p0) {
    int slot = base + __popcll(m0 & lt);
    if (slot < CAPIMG) gk[slot] = pack_key(sc0, (unsigned)(n * C_ + lane));
    atomicAdd(&gh[bucket_of_bits(__float_as_uint(sc0))], 1u);
  }
  if (p1) {
    int slot = base + c0 + __popcll(m1 & lt);
    if (slot < CAPIMG) gk[slot] = pack_key(sc1, (unsigned)(n * C_ + 64 + lane));
    atomicAdd(&gh[bucket_of_bits(__float_as_uint(sc1))], 1u);
  }
}

// ---------------- nmsA: hot path, contiguous ingest ----------------
// LDS map (17248 B): SS u64[256]@0; U u64[260]@2048; rb u64[256*4]@4128;
// bxA float4[256]@12320; outl int[128]@16416; misc int[16]@16928;
// s_coarse int[64]@16992.  misc: 0=T_A 2=S_A 3=Mtot 4=cnt 6=nkept 7=ovf
__global__ __launch_bounds__(1024) void nmsA_kernel(
    const float* __restrict__ reg, const float* __restrict__ props,
    const int* __restrict__ hw, const u64* __restrict__ gkeys,
    const u32* __restrict__ gcur, const u32* __restrict__ ghist,
    int* __restrict__ gflag, float* __restrict__ out) {
  __shared__ u64 lds8[2156];  // 17248 B
  char* bp = (char*)lds8;
  u64* SS = (u64*)bp;
  u64* U = (u64*)(bp + 2048);
  u64* rb = (u64*)(bp + 4128);
  float4* bxA = (float4*)(bp + 12320);
  int* outl = (int*)(bp + 16416);
  int* misc = (int*)(bp + 16928);
  int* s_coarse = (int*)(bp + 16992);

  const int b = blockIdx.x, tid = threadIdx.x;
  const int wv = tid >> 6, lane = tid & 63;

  float h = (float)hw[b * 2 + 0];
  float w = (float)hw[b * 2 + 1];
  float offscale = fmaxf(h, w) + 1.0f;

  if (tid < 16) misc[tid] = 0;
  if (tid >= NG && tid < 64) s_coarse[tid] = 0;  // waves 12..15 fill [0,NG)

  // ---- Phase A: all waves stage contiguous keys into regs (one latency
  //      round); waves 12..15 also coarse-sum the fine histogram. ----
  const u64* keys = gkeys + (size_t)b * CAPIMG;
  const u32 Mraw = gcur[b];
  const int M = min((int)Mraw, CAPIMG);
  if (tid == 0 && Mraw > (u32)CAPIMG) misc[7] = 1;
  u64 kreg[KPT];
#pragma unroll
  for (int r = 0; r < KPT; r++) {
    int idx = tid + (r << 10);
    kreg[r] = (idx < M) ? keys[idx] : 0ULL;
  }
  if (wv >= 12) {
    // 37 groups over waves 12..15: 10,9,9,9
    int g0 = (wv == 12) ? 0 : 10 + (wv - 13) * 9;
    int g1 = (wv == 12) ? 10 : g0 + 9;
    for (int g2 = g0; g2 < g1; g2++) {
      int v = (int)ghist[b * NBPAD + ((g2 << 6) | lane)];
#pragma unroll
      for (int o = 32; o; o >>= 1) v += __shfl_xor(v, o);
      if (lane == 0) s_coarse[g2] = v;
    }
  }
  __syncthreads();

  // ---- Phase B: wave 0 computes T_A (cum>=TARGET), S_A, Mtot. ----
  if (tid < 64) {
    int v = s_coarse[lane];
#pragma unroll
    for (int off = 1; off < 64; off <<= 1) {
      int src = lane + off;
      int o = __shfl(v, src < 64 ? src : 63);
      if (src < 64) v += o;
    }
    int Mtot = __shfl(v, 0);
    u64 pm = __ballot(v >= TARGET);
    int T_A = 0, S_A;
    if (pm) {
      int gs = 63 - __builtin_clzll(pm);
      int beyond = __shfl(v, gs + 1);
      int fv = (int)ghist[b * NBPAD + ((gs << 6) | lane)];
#pragma unroll
      for (int off = 1; off < 64; off <<= 1) {
        int src = lane + off;
        int o = __shfl(fv, src < 64 ? src : 63);
        if (src < 64) fv += o;
      }
      int cum = beyond + fv;
      u64 pm2 = __ballot(cum >= TARGET);
      int tr = 63 - __builtin_clzll(pm2);
      T_A = (gs << 6) + tr;
      S_A = __shfl(cum, tr);
    } else {
      S_A = Mtot;
    }
    if (lane == 0) { misc[0] = T_A; misc[2] = S_A; misc[3] = Mtot; }
  }
  __syncthreads();

  const int T_A = misc[0], S_A = misc[2], Mtot = misc[3];
  bool modeB = (S_A > CAPA) || (misc[7] != 0);
  int K = 0, nkept = 0;

  if (!modeB) {
    // ---- Phase C: filter staged keys by T_A, ballot-compact into U. ----
    {
      const u64 lt = (1ull << lane) - 1;
#pragma unroll
      for (int r = 0; r < KPT; r++) {
        int idx = tid + (r << 10);
        bool pr = (idx < M) &&
                  (bucket_of_bits((u32)(kreg[r] >> 32)) >= T_A);
        u64 mk = __ballot(pr);
        if (mk) {
          int wbase = 0;
          if (lane == 0) wbase = atomicAdd(&misc[4], __popcll(mk));
          wbase = __shfl(wbase, 0);
          if (pr) {
            int pos = wbase + __popcll(mk & lt);
            if (pos < CAPA) U[pos] = kreg[r];
          }
        }
      }
    }
    __syncthreads();
    int S = misc[4];
    if (S > CAPA) S = CAPA;

    // ---- Phase D: rank-scatter sort U -> SS. ----
    if (tid == 0 && (S & 1)) U[S] = 0ULL;
    __syncthreads();
    if (tid < S) {
      u64 k1 = U[tid];
      int r1 = 0;
      const ulonglong2* Uu2 = (const ulonglong2*)U;
      int half = (S + 1) >> 1;
      for (int k = 0; k < half; k++) {
        ulonglong2 kk = Uu2[k];
        r1 += (kk.x > k1) + (kk.y > k1);
      }
      SS[r1] = k1;
    }
    __syncthreads();
    K = S;
    for (int j = tid; j < K; j += 1024)
      bxA[j] = decode_one(SS[j], reg, props, b, h, w, offscale);
    __syncthreads();

    // ---- Phase E: suppression bit-matrix (4 words/row). ----
    int nwords = (S + 63) >> 6;
    int ntiles = nwords * (nwords + 1) / 2;
    for (int t = wv; t < ntiles; t += 16) {
      int ti = 0, rem = t;
      while (rem >= nwords - ti) { rem -= nwords - ti; ti++; }
      int tj = ti + rem;
      int i = (ti << 6) + lane;
      float4 bi4 = bxA[i];
      float ai = (bi4.z - bi4.x) * (bi4.w - bi4.y);
      u64 bits = 0;
      int jbase = tj << 6;
      int jcount = min(64, S - jbase);
      for (int jj = 0; jj < jcount; jj++) {
        int j = jbase + jj;
        float4 bj = bxA[j];
        float aj = (bj.z - bj.x) * (bj.w - bj.y);
        float iw = fmaxf(fminf(bi4.z, bj.z) - fmaxf(bi4.x, bj.x), 0.0f);
        float ih = fmaxf(fminf(bi4.w, bj.w) - fmaxf(bi4.y, bj.y), 0.0f);
        float inter = iw * ih;
        float iou = inter / (ai + aj - inter + 1e-6f);
        if (j > i && iou > 0.5f) bits |= (1ull << jj);
      }
      if (i < S) rb[i * 4 + tj] = bits;
    }
    __syncthreads();

    // ---- Phase F: greedy bit-scan (wave 0), speculative i+1 prefetch. ----
    if (tid < 64) {
      int nw7 = (S + 63) >> 6;
      u64 alive = 0;
      if (lane < nw7) {
        alive = ~0ull;
        int remb = S & 63;
        if (lane == nw7 - 1 && remb) alive = (1ull << remb) - 1;
      }
      int nk = 0;
      if (S > 0) {
        int i = 0;
        u64 row = (lane < nw7) ? rb[0 * 4 + lane] : 0ull;
        for (;;) {
          if (lane == 0) outl[nk] = i;
          nk++;
          if (nk >= MAXDET) break;
          if (lane == (i >> 6)) alive &= ~(1ull << (i & 63));
          u64 rowSpec = (i + 1 < S && lane < nw7) ? rb[(i + 1) * 4 + lane] : 0ull;
          u64 a2 = alive & ~row;
          alive = a2;
          int cnd = a2 ? ((lane << 6) + (int)__builtin_ctzll(a2)) : BIGI;
          int m8 = dpp_min8(cnd);
          int ni = __builtin_amdgcn_readfirstlane(m8);
          if (ni >= BIGI) break;
          row = (ni == i + 1) ? rowSpec
                              : ((lane < nw7) ? rb[ni * 4 + lane] : 0ull);
          i = ni;
        }
      }
      if (lane == 0) misc[6] = nk;
    }
    __syncthreads();
    nkept = misc[6];
    if (nkept < MAXDET && K < Mtot && K < KPRE) modeB = true;
  }

  if (tid == 0) gflag[b] = modeB ? 1 : 0;  // unconditional each launch
  if (modeB) return;  // nmsB writes this image's output

  // Output: boxes [B,100,4] | scores [B,100] | labels [B,100].
  float* oBox = out;
  float* oSc = out + B_ * MAXDET * 4;
  float* oLb = out + B_ * MAXDET * 5;
  for (int k2 = tid; k2 < MAXDET; k2 += 1024) {
    float4 bb = make_float4(0.0f, 0.0f, 0.0f, 0.0f);
    float sv = 0.0f, lv = -1.0f;
    if (k2 < nkept) {
      int idx = outl[k2];
      u64 kk = SS[idx];
      sv = __uint_as_float((u32)(kk >> 32));
      unsigned fi = 0xFFFFFFFFu - (u32)kk;
      int c = (int)(fi % (unsigned)C_);
      float off = (float)c * offscale;
      float4 ob = bxA[idx];
      bb = make_float4(ob.x - off, ob.y - off, ob.z - off, ob.w - off);
      lv = (float)c;
    }
    oBox[(b * MAXDET + k2) * 4 + 0] = bb.x;
    oBox[(b * MAXDET + k2) * 4 + 1] = bb.y;
    oBox[(b * MAXDET + k2) * 4 + 2] = bb.z;
    oBox[(b * MAXDET + k2) * 4 + 3] = bb.w;
    oSc[b * MAXDET + k2] = sv;
    oLb[b * MAXDET + k2] = lv;
  }
}

// ---------------- nmsB: exact fallback (flag-gated, contiguous) ----------------
__global__ __launch_bounds__(1024) void nmsB_kernel(
    const float* __restrict__ reg, const float* __restrict__ props,
    const int* __restrict__ hw, const u64* __restrict__ gkeys,
    const u32* __restrict__ gcur, const int* __restrict__ gflag,
    float* __restrict__ out) {
  const int b = blockIdx.x, tid = threadIdx.x;
  if (gflag[b] == 0) return;  // block-uniform fast exit (the normal case)

  __shared__ u64 lds8[7952];
  char* bp = (char*)lds8;
  u32* hist = (u32*)(bp + 0);          // [0,9472)
  u64* U2 = (u64*)(bp + 9472);         // 2048 keys
  u64* SSB = (u64*)(bp + 25856);       // 2048 sorted
  int* outl = (int*)(bp + 42240);      // 128
  int* misc = (int*)(bp + 42752);      // 16
  const int lane = tid & 63;

  float h = (float)hw[b * 2 + 0];
  float w = (float)hw[b * 2 + 1];
  float offscale = fmaxf(h, w) + 1.0f;

  const u64* keys = gkeys + (size_t)b * CAPIMG;
  const int M = min((int)gcur[b], CAPIMG);

  for (int i = tid; i < NBPAD; i += 1024) hist[i] = 0;
  if (tid < 16) misc[tid] = 0;
  __syncthreads();

  // Histogram from contiguous keys.
  for (int idx = tid; idx < M; idx += 1024) {
    u64 key = keys[idx];
    int bi = min(max((int)(key >> KSHIFT) - HBASE, 0), NB - 1);
    atomicAdd(&hist[bi], 1u);
  }
  __syncthreads();

  // T_B: serial suffix walk (cold path).
  if (tid == 0) {
    int acc = 0, tb = 0;
    for (int bi = NB - 1; bi >= 0; bi--) {
      acc += (int)hist[bi];
      if (acc >= KPRE) { tb = bi; break; }
    }
    if (acc > CAPB) tb = min(tb + 1, NB - 1);  // fat-bucket guard
    misc[1] = tb;
    misc[4] = 0;
  }
  __syncthreads();
  int T_B = misc[1];

  // Compact bucket >= T_B into U2 (ballot-aggregated).
  for (int idx0 = 0; idx0 < M; idx0 += 1024) {
    int idx = idx0 + tid;
    bool pred = false;
    u64 key = 0;
    if (idx < M) {
      key = keys[idx];
      int bi = min(max((int)(key >> KSHIFT) - HBASE, 0), NB - 1);
      pred = (bi >= T_B);
    }
    u64 mk = __ballot(pred);
    if (mk) {
      int wbase = 0;
      if (lane == 0) wbase = atomicAdd(&misc[4], __popcll(mk));
      wbase = __shfl(wbase, 0);
      if (pred) {
        int pos = wbase + __popcll(mk & ((1ull << lane) - 1));
        if (pos < CAPB) U2[pos] = key;
      }
    }
  }
  __syncthreads();
  int S = misc[4];
  if (S > CAPB) S = CAPB;
  {  // rank-scatter sort, 2 keys/thread
    int j1 = tid, j2 = tid + 1024;
    u64 k1 = (j1 < S) ? U2[j1] : 0ULL;
    u64 k2 = (j2 < S) ? U2[j2] : 0ULL;
    int r1 = 0, r2 = 0;
    for (int k = 0; k < S; k++) {
      u64 kk = U2[k];
      r1 += (kk > k1);
      r2 += (kk > k2);
    }
    __syncthreads();
    if (j1 < S) SSB[r1] = k1;
    if (j2 < S) SSB[r2] = k2;
  }
  __syncthreads();
  int K = (S < KPRE) ? S : KPRE;  // exact top-2000 (or all if fewer)
  // NMS with per-thread register boxes.
  int j1 = tid, j2 = tid + 1024;
  bool kp1 = (j1 < K), kp2 = (j2 < K);
  float4 bb1 = kp1 ? decode_one(SSB[j1], reg, props, b, h, w, offscale)
                   : make_float4(0, 0, 0, 0);
  float4 bb2 = kp2 ? decode_one(SSB[j2], reg, props, b, h, w, offscale)
                   : make_float4(0, 0, 0, 0);
  int nk = 0;
  if (K > 0) {
    int i = 0;
    for (;;) {
      if (tid == 0) { outl[nk] = i; misc[5] = K; }
      nk++;
      if (nk >= MAXDET) break;
      __syncthreads();
      float4 tb = decode_one(SSB[i], reg, props, b, h, w, offscale);
      float ai = (tb.z - tb.x) * (tb.w - tb.y);
      int ln = K;
      if (kp1 && j1 > i) {
        float aj = (bb1.z - bb1.x) * (bb1.w - bb1.y);
        float iw = fmaxf(fminf(tb.z, bb1.z) - fmaxf(tb.x, bb1.x), 0.0f);
        float ih = fmaxf(fminf(tb.w, bb1.w) - fmaxf(tb.y, bb1.y), 0.0f);
        float inter = iw * ih;
        float iou = inter / (ai + aj - inter + 1e-6f);
        if (iou > 0.5f) kp1 = false;
        else ln = min(ln, j1);
      }
      if (kp2 && j2 > i) {
        float aj = (bb2.z - bb2.x) * (bb2.w - bb2.y);
        float iw = fmaxf(fminf(tb.z, bb2.z) - fmaxf(tb.x, bb2.x), 0.0f);
        float ih = fmaxf(fminf(tb.w, bb2.w) - fmaxf(tb.y, bb2.y), 0.0f);
        float inter = iw * ih;
        float iou = inter / (ai + aj - inter + 1e-6f);
        if (iou > 0.5f) kp2 = false;
        else ln = min(ln, j2);
      }
#pragma unroll
      for (int off = 32; off; off >>= 1) ln = min(ln, __shfl_xor(ln, off));
      if ((tid & 63) == 0 && ln < K) atomicMin(&misc[5], ln);
      __syncthreads();
      int ni = misc[5];
      __syncthreads();
      if (ni >= K) break;
      i = ni;
    }
  }
  if (tid == 0) misc[6] = nk;
  __syncthreads();
  int nkept = misc[6];

  float* oBox = out;
  float* oSc = out + B_ * MAXDET * 4;
  float* oLb = out + B_ * MAXDET * 5;
  for (int k2 = tid; k2 < MAXDET; k2 += 1024) {
    float4 bb = make_float4(0.0f, 0.0f, 0.0f, 0.0f);
    float sv = 0.0f, lv = -1.0f;
    if (k2 < nkept) {
      int idx = outl[k2];
      u64 kk = SSB[idx];
      sv = __uint_as_float((u32)(kk >> 32));
      unsigned fi = 0xFFFFFFFFu - (u32)kk;
      int c = (int)(fi % (unsigned)C_);
      float off = (float)c * offscale;
      float4 ob = decode_one(kk, reg, props, b, h, w, offscale);
      bb = make_float4(ob.x - off, ob.y - off, ob.z - off, ob.w - off);
      lv = (float)c;
    }
    oBox[(b * MAXDET + k2) * 4 + 0] = bb.x;
    oBox[(b * MAXDET + k2) * 4 + 1] = bb.y;
    oBox[(b * MAXDET + k2) * 4 + 2] = bb.z;
    oBox[(b * MAXDET + k2) * 4 + 3] = bb.w;
    oSc[b * MAXDET + k2] = sv;
    oLb[b * MAXDET + k2] = lv;
  }
}

extern "C" void kernel_launch(void* const* d_in, const int* in_sizes, int n_in,
                              void* d_out, int out_size, void* d_ws, size_t ws_size,
                              hipStream_t stream) {
  const float* cls = (const float*)d_in[0];    // [B,N,81] f32
  const float* reg = (const float*)d_in[1];    // [B,N,320] f32
  const float* props = (const float*)d_in[2];  // [B,N,4] f32
  const int* hw = (const int*)d_in[3];         // [B,2] i32
  float* out = (float*)d_out;                  // 2400 f32

  u32* gcur = (u32*)((char*)d_ws + WS_GCUR);
  u32* ghist = (u32*)((char*)d_ws + WS_GHIST);
  int* gflag = (int*)((char*)d_ws + WS_GFLAG);
  u64* gkeys = (u64*)((char*)d_ws + WS_GKEYS);

  hipMemsetAsync(d_ws, 0, WS_ZEND, stream);
  cand_kernel<<<B_ * BPI, 1024, 0, stream>>>(cls, gkeys, gcur, ghist);
  nmsA_kernel<<<B_, 1024, 0, stream>>>(reg, props, hw, gkeys, gcur, ghist,
                                       gflag, out);
  nmsB_kernel<<<B_, 1024, 0, stream>>>(reg, props, hw, gkeys, gcur, gflag, out);
}